// Round 1
// baseline (3543.289 us; speedup 1.0000x reference)
//
#include <hip/hip_runtime.h>
#include <math.h>

namespace {
constexpr int B_ = 4, N_ = 2048, D_ = 1024, H_ = 16, DH_ = 64;
constexpr int M_ = B_ * N_;   // 8192 rows of x
}

__device__ inline float dot4(float4 a, float4 b) {
    return a.x * b.x + a.y * b.y + a.z * b.z + a.w * b.w;
}

// ---------------------------------------------------------------------------
// SGEMM: C(64x64 tile) = A(MxK) * W(KxN) + bias. 256 threads, 4x4 microtile,
// BK=16. LDS stride 68 keeps ds_read_b128 conflict-free (chunk=(k*17+t)%32).
// QKV variant writes output permuted to (B,H,N,DH); h == blockIdx.y since the
// 64-wide column tile exactly spans one head.
// ---------------------------------------------------------------------------
__global__ __launch_bounds__(256) void qkv_gemm(
        const float* __restrict__ x,
        const float* __restrict__ Wq, const float* __restrict__ bq,
        const float* __restrict__ Wk, const float* __restrict__ bk,
        const float* __restrict__ Wv, const float* __restrict__ bv,
        float* __restrict__ qo, float* __restrict__ ko, float* __restrict__ vo)
{
    const float* W; const float* bias; float* dst;
    if (blockIdx.z == 0)      { W = Wq; bias = bq; dst = qo; }
    else if (blockIdx.z == 1) { W = Wk; bias = bk; dst = ko; }
    else                      { W = Wv; bias = bv; dst = vo; }

    __shared__ __align__(16) float As[16][68];   // As[k][m]
    __shared__ __align__(16) float Bs[16][68];   // Bs[k][n]
    const int tid = threadIdx.x;
    const int tx = tid & 15, ty = tid >> 4;
    const int row0 = blockIdx.x * 64;
    const int col0 = blockIdx.y * 64;

    float acc[4][4] = {};

    for (int k0 = 0; k0 < D_; k0 += 16) {
        {   // stage A: 64 rows x 16 k (coalesced along k)
            const int k = tid & 15, m0 = tid >> 4;
            #pragma unroll
            for (int p = 0; p < 4; ++p)
                As[k][m0 + 16 * p] = x[(size_t)(row0 + m0 + 16 * p) * D_ + (k0 + k)];
        }
        {   // stage W: 16 k x 64 cols (coalesced along cols)
            const int cc = tid & 63, kk = tid >> 6;
            #pragma unroll
            for (int p = 0; p < 4; ++p)
                Bs[kk + 4 * p][cc] = W[(size_t)(k0 + kk + 4 * p) * D_ + (col0 + cc)];
        }
        __syncthreads();
        #pragma unroll
        for (int k = 0; k < 16; ++k) {
            const float4 a = *reinterpret_cast<const float4*>(&As[k][ty * 4]);
            const float4 b = *reinterpret_cast<const float4*>(&Bs[k][tx * 4]);
            const float av[4] = {a.x, a.y, a.z, a.w};
            const float bv4[4] = {b.x, b.y, b.z, b.w};
            #pragma unroll
            for (int i = 0; i < 4; ++i)
                #pragma unroll
                for (int j = 0; j < 4; ++j)
                    acc[i][j] += av[i] * bv4[j];
        }
        __syncthreads();
    }

    const int h = blockIdx.y;   // column tile == head
    const float4 bias4 = *reinterpret_cast<const float4*>(&bias[col0 + tx * 4]);
    #pragma unroll
    for (int i = 0; i < 4; ++i) {
        const int gr = row0 + ty * 4 + i;
        const int b = gr >> 11;          // / N_
        const int n = gr & (N_ - 1);
        float4 o;
        o.x = acc[i][0] + bias4.x;
        o.y = acc[i][1] + bias4.y;
        o.z = acc[i][2] + bias4.z;
        o.w = acc[i][3] + bias4.w;
        *reinterpret_cast<float4*>(
            &dst[((size_t)(b * H_ + h) * N_ + n) * DH_ + tx * 4]) = o;
    }
}

// ---------------------------------------------------------------------------
// Output projection: out = ctx(Mx1024) * Wo + bo, row-major output.
// ---------------------------------------------------------------------------
__global__ __launch_bounds__(256) void out_gemm(
        const float* __restrict__ A,
        const float* __restrict__ W, const float* __restrict__ bias,
        float* __restrict__ out)
{
    __shared__ __align__(16) float As[16][68];
    __shared__ __align__(16) float Bs[16][68];
    const int tid = threadIdx.x;
    const int tx = tid & 15, ty = tid >> 4;
    const int row0 = blockIdx.x * 64;
    const int col0 = blockIdx.y * 64;

    float acc[4][4] = {};

    for (int k0 = 0; k0 < D_; k0 += 16) {
        {
            const int k = tid & 15, m0 = tid >> 4;
            #pragma unroll
            for (int p = 0; p < 4; ++p)
                As[k][m0 + 16 * p] = A[(size_t)(row0 + m0 + 16 * p) * D_ + (k0 + k)];
        }
        {
            const int cc = tid & 63, kk = tid >> 6;
            #pragma unroll
            for (int p = 0; p < 4; ++p)
                Bs[kk + 4 * p][cc] = W[(size_t)(k0 + kk + 4 * p) * D_ + (col0 + cc)];
        }
        __syncthreads();
        #pragma unroll
        for (int k = 0; k < 16; ++k) {
            const float4 a = *reinterpret_cast<const float4*>(&As[k][ty * 4]);
            const float4 b = *reinterpret_cast<const float4*>(&Bs[k][tx * 4]);
            const float av[4] = {a.x, a.y, a.z, a.w};
            const float bv4[4] = {b.x, b.y, b.z, b.w};
            #pragma unroll
            for (int i = 0; i < 4; ++i)
                #pragma unroll
                for (int j = 0; j < 4; ++j)
                    acc[i][j] += av[i] * bv4[j];
        }
        __syncthreads();
    }

    const float4 bias4 = *reinterpret_cast<const float4*>(&bias[col0 + tx * 4]);
    #pragma unroll
    for (int i = 0; i < 4; ++i) {
        const int gr = row0 + ty * 4 + i;
        float4 o;
        o.x = acc[i][0] + bias4.x;
        o.y = acc[i][1] + bias4.y;
        o.z = acc[i][2] + bias4.z;
        o.w = acc[i][3] + bias4.w;
        *reinterpret_cast<float4*>(&out[(size_t)gr * D_ + col0 + tx * 4]) = o;
    }
}

// ---------------------------------------------------------------------------
// Flash-style causal attention. Grid: (N/64 q-tiles, B*H). 256 threads.
// Thread t owns query row r = t>>2 and column-quarter c = t&3 (16 output dims).
// Q tile staged via LDS once, hoisted to 16xfloat4 registers; the Q buffer is
// then reused to hold P each K-tile. Online softmax state per row replicated
// across the 4 c-lanes, reduced with __shfl_xor(1|2) (same wave: lanes 4r..4r+3).
// ---------------------------------------------------------------------------
__global__ __launch_bounds__(256) void attn(
        const float* __restrict__ Q, const float* __restrict__ K,
        const float* __restrict__ V, float* __restrict__ ctx)
{
    const int qb = blockIdx.x;          // 0..31
    const int bh = blockIdx.y;          // 0..63
    const int b = bh >> 4, h = bh & 15;
    const int tid = threadIdx.x;
    const int r = tid >> 2;             // query row in tile
    const int c = tid & 3;              // column quarter

    __shared__ __align__(16) float QPs[64][68];  // Q staging, then P
    __shared__ __align__(16) float Ks[64][68];
    __shared__ __align__(16) float Vs[64][68];

    // --- stage Q tile (coalesced), hoist own row to registers ---
    {
        const float4* Qg = reinterpret_cast<const float4*>(
            Q + ((size_t)bh * N_ + qb * 64) * DH_);
        #pragma unroll
        for (int p = 0; p < 4; ++p) {
            const int fi = p * 256 + tid;
            const int j = fi >> 4, d4 = fi & 15;
            *reinterpret_cast<float4*>(&QPs[j][d4 * 4]) = Qg[fi];
        }
    }
    __syncthreads();
    float4 qreg[16];
    #pragma unroll
    for (int i = 0; i < 16; ++i)
        qreg[i] = *reinterpret_cast<const float4*>(&QPs[r][i * 4]);

    float o[16];
    #pragma unroll
    for (int i = 0; i < 16; ++i) o[i] = 0.f;
    float m_run = -INFINITY, l_run = 0.f;
    const int q_glob = qb * 64 + r;
    const float scale = 0.125f;   // 1/sqrt(64)

    for (int kb = 0; kb <= qb; ++kb) {
        __syncthreads();   // prior PV readers done with Vs / QPs(P)
        {
            const size_t kbase = ((size_t)bh * N_ + kb * 64) * DH_;
            const float4* Kg = reinterpret_cast<const float4*>(K + kbase);
            const float4* Vg = reinterpret_cast<const float4*>(V + kbase);
            #pragma unroll
            for (int p = 0; p < 4; ++p) {
                const int fi = p * 256 + tid;
                const int j = fi >> 4, d4 = fi & 15;
                *reinterpret_cast<float4*>(&Ks[j][d4 * 4]) = Kg[fi];
                *reinterpret_cast<float4*>(&Vs[j][d4 * 4]) = Vg[fi];
            }
        }
        __syncthreads();

        // --- S = scale * Q K^T for own 16 columns, causal mask ---
        float s[16];
        #pragma unroll
        for (int jj = 0; jj < 16; ++jj) {
            const int j = c * 16 + jj;
            const int k_glob = kb * 64 + j;
            float a = 0.f;
            #pragma unroll
            for (int i = 0; i < 16; ++i)
                a += dot4(qreg[i], *reinterpret_cast<const float4*>(&Ks[j][i * 4]));
            s[jj] = (k_glob <= q_glob) ? a * scale : -INFINITY;
        }

        // --- online softmax (row state replicated over 4 c-lanes) ---
        float lm = -INFINITY;
        #pragma unroll
        for (int jj = 0; jj < 16; ++jj) lm = fmaxf(lm, s[jj]);
        lm = fmaxf(lm, __shfl_xor(lm, 1));
        lm = fmaxf(lm, __shfl_xor(lm, 2));
        const float m_new = fmaxf(m_run, lm);
        const float alpha = __expf(m_run - m_new);   // 0 on first tile
        float psum = 0.f;
        #pragma unroll
        for (int jj = 0; jj < 16; ++jj) {
            const float p = __expf(s[jj] - m_new);   // exp(-inf)=0 for masked
            s[jj] = p;
            psum += p;
        }
        psum += __shfl_xor(psum, 1);
        psum += __shfl_xor(psum, 2);
        l_run = l_run * alpha + psum;
        m_run = m_new;
        #pragma unroll
        for (int i = 0; i < 16; ++i) o[i] *= alpha;
        #pragma unroll
        for (int jj = 0; jj < 16; ++jj) QPs[r][c * 16 + jj] = s[jj];
        __syncthreads();

        // --- O += P * V for own 16 dims ---
        for (int kk = 0; kk < 64; ++kk) {
            const float p = QPs[r][kk];
            #pragma unroll
            for (int q4 = 0; q4 < 4; ++q4) {
                const float4 vv =
                    *reinterpret_cast<const float4*>(&Vs[kk][c * 16 + q4 * 4]);
                o[q4 * 4 + 0] += p * vv.x;
                o[q4 * 4 + 1] += p * vv.y;
                o[q4 * 4 + 2] += p * vv.z;
                o[q4 * 4 + 3] += p * vv.w;
            }
        }
    }

    // --- normalize and write ctx in (B,N,D) layout ---
    const float inv = 1.0f / l_run;
    float* dst = ctx + ((size_t)(b * N_) + q_glob) * D_ + h * DH_ + c * 16;
    #pragma unroll
    for (int q4 = 0; q4 < 4; ++q4) {
        float4 o4 = make_float4(o[q4 * 4 + 0] * inv, o[q4 * 4 + 1] * inv,
                                o[q4 * 4 + 2] * inv, o[q4 * 4 + 3] * inv);
        *reinterpret_cast<float4*>(&dst[q4 * 4]) = o4;
    }
}

extern "C" void kernel_launch(void* const* d_in, const int* in_sizes, int n_in,
                              void* d_out, int out_size, void* d_ws, size_t ws_size,
                              hipStream_t stream) {
    const float* x  = (const float*)d_in[0];
    const float* Wq = (const float*)d_in[1];
    const float* bq = (const float*)d_in[2];
    const float* Wk = (const float*)d_in[3];
    const float* bk = (const float*)d_in[4];
    const float* Wv = (const float*)d_in[5];
    const float* bv = (const float*)d_in[6];
    const float* Wo = (const float*)d_in[7];
    const float* bo = (const float*)d_in[8];
    float* out = (float*)d_out;

    // workspace: Q | K | V (B,H,N,DH) + ctx (B,N,D) = 4 * 33.5 MB = 134 MB
    float* ws  = (float*)d_ws;
    float* q   = ws;
    float* k   = ws + 1 * (size_t)M_ * D_;
    float* v   = ws + 2 * (size_t)M_ * D_;
    float* ctx = ws + 3 * (size_t)M_ * D_;

    qkv_gemm<<<dim3(M_ / 64, D_ / 64, 3), 256, 0, stream>>>(
        x, Wq, bq, Wk, bk, Wv, bv, q, k, v);
    attn<<<dim3(N_ / 64, B_ * H_), 256, 0, stream>>>(q, k, v, ctx);
    out_gemm<<<dim3(M_ / 64, D_ / 64), 256, 0, stream>>>(ctx, Wo, bo, out);
}

// Round 2
// 1246.415 us; speedup vs baseline: 2.8428x; 2.8428x over previous
//
#include <hip/hip_runtime.h>
#include <hip/hip_bf16.h>
#include <math.h>

namespace {
constexpr int B_ = 4, N_ = 2048, D_ = 1024, H_ = 16, DH_ = 64;
constexpr int M_ = B_ * N_;   // 8192 rows of x
}

typedef __bf16 bf16x8 __attribute__((ext_vector_type(8)));
typedef __bf16 bf16x4 __attribute__((ext_vector_type(4)));
typedef float  f32x4  __attribute__((ext_vector_type(4)));

// ---------------------------------------------------------------------------
// SGEMM (fp32 math): C(64x64) = A*W + bias. 256 thr, 4x4 microtile, BK=16.
// Q/K written bf16 in (B,H,N,DH); V written bf16 TRANSPOSED in (B,H,DH,N)
// so the attention kernel can read MFMA B-fragments contiguously.
// ---------------------------------------------------------------------------
__global__ __launch_bounds__(256) void qkv_gemm(
        const float* __restrict__ x,
        const float* __restrict__ Wq, const float* __restrict__ bq,
        const float* __restrict__ Wk, const float* __restrict__ bk,
        const float* __restrict__ Wv, const float* __restrict__ bv,
        __bf16* __restrict__ qo, __bf16* __restrict__ ko, __bf16* __restrict__ vo)
{
    const float* W; const float* bias;
    if (blockIdx.z == 0)      { W = Wq; bias = bq; }
    else if (blockIdx.z == 1) { W = Wk; bias = bk; }
    else                      { W = Wv; bias = bv; }

    __shared__ __align__(16) float As[16][68];   // As[k][m]
    __shared__ __align__(16) float Bs[16][68];   // Bs[k][n]
    const int tid = threadIdx.x;
    const int tx = tid & 15, ty = tid >> 4;
    const int row0 = blockIdx.x * 64;
    const int col0 = blockIdx.y * 64;

    float acc[4][4] = {};

    for (int k0 = 0; k0 < D_; k0 += 16) {
        {   // stage A: 64 rows x 16 k
            const int k = tid & 15, m0 = tid >> 4;
            #pragma unroll
            for (int p = 0; p < 4; ++p)
                As[k][m0 + 16 * p] = x[(size_t)(row0 + m0 + 16 * p) * D_ + (k0 + k)];
        }
        {   // stage W: 16 k x 64 cols
            const int cc = tid & 63, kk = tid >> 6;
            #pragma unroll
            for (int p = 0; p < 4; ++p)
                Bs[kk + 4 * p][cc] = W[(size_t)(k0 + kk + 4 * p) * D_ + (col0 + cc)];
        }
        __syncthreads();
        #pragma unroll
        for (int k = 0; k < 16; ++k) {
            const float4 a = *reinterpret_cast<const float4*>(&As[k][ty * 4]);
            const float4 b = *reinterpret_cast<const float4*>(&Bs[k][tx * 4]);
            const float av[4] = {a.x, a.y, a.z, a.w};
            const float bv4[4] = {b.x, b.y, b.z, b.w};
            #pragma unroll
            for (int i = 0; i < 4; ++i)
                #pragma unroll
                for (int j = 0; j < 4; ++j)
                    acc[i][j] += av[i] * bv4[j];
        }
        __syncthreads();
    }

    const int h = blockIdx.y;   // 64-wide column tile == one head
    const float4 bias4 = *reinterpret_cast<const float4*>(&bias[col0 + tx * 4]);
    const float bb[4] = {bias4.x, bias4.y, bias4.z, bias4.w};

    if (blockIdx.z == 2) {
        // V: transposed store (B,H,DH,N). Per col j: 4 consecutive rows packed.
        const int gr0 = row0 + ty * 4;
        const int b = gr0 >> 11;
        const int n0 = gr0 & (N_ - 1);
        #pragma unroll
        for (int j = 0; j < 4; ++j) {
            const int dh = tx * 4 + j;
            bf16x4 pv;
            #pragma unroll
            for (int i = 0; i < 4; ++i) pv[i] = (__bf16)(acc[i][j] + bb[j]);
            *reinterpret_cast<bf16x4*>(
                &vo[((size_t)(b * H_ + h) * DH_ + dh) * N_ + n0]) = pv;
        }
    } else {
        __bf16* dst = (blockIdx.z == 0) ? qo : ko;
        #pragma unroll
        for (int i = 0; i < 4; ++i) {
            const int gr = row0 + ty * 4 + i;
            const int b = gr >> 11;
            const int n = gr & (N_ - 1);
            bf16x4 pv;
            #pragma unroll
            for (int j = 0; j < 4; ++j) pv[j] = (__bf16)(acc[i][j] + bb[j]);
            *reinterpret_cast<bf16x4*>(
                &dst[((size_t)(b * H_ + h) * N_ + n) * DH_ + tx * 4]) = pv;
        }
    }
}

// ---------------------------------------------------------------------------
// Output projection (fp32): out = ctx(Mx1024) * Wo + bo.
// ---------------------------------------------------------------------------
__global__ __launch_bounds__(256) void out_gemm(
        const float* __restrict__ A,
        const float* __restrict__ W, const float* __restrict__ bias,
        float* __restrict__ out)
{
    __shared__ __align__(16) float As[16][68];
    __shared__ __align__(16) float Bs[16][68];
    const int tid = threadIdx.x;
    const int tx = tid & 15, ty = tid >> 4;
    const int row0 = blockIdx.x * 64;
    const int col0 = blockIdx.y * 64;

    float acc[4][4] = {};

    for (int k0 = 0; k0 < D_; k0 += 16) {
        {
            const int k = tid & 15, m0 = tid >> 4;
            #pragma unroll
            for (int p = 0; p < 4; ++p)
                As[k][m0 + 16 * p] = A[(size_t)(row0 + m0 + 16 * p) * D_ + (k0 + k)];
        }
        {
            const int cc = tid & 63, kk = tid >> 6;
            #pragma unroll
            for (int p = 0; p < 4; ++p)
                Bs[kk + 4 * p][cc] = W[(size_t)(k0 + kk + 4 * p) * D_ + (col0 + cc)];
        }
        __syncthreads();
        #pragma unroll
        for (int k = 0; k < 16; ++k) {
            const float4 a = *reinterpret_cast<const float4*>(&As[k][ty * 4]);
            const float4 b = *reinterpret_cast<const float4*>(&Bs[k][tx * 4]);
            const float av[4] = {a.x, a.y, a.z, a.w};
            const float bv4[4] = {b.x, b.y, b.z, b.w};
            #pragma unroll
            for (int i = 0; i < 4; ++i)
                #pragma unroll
                for (int j = 0; j < 4; ++j)
                    acc[i][j] += av[i] * bv4[j];
        }
        __syncthreads();
    }

    const float4 bias4 = *reinterpret_cast<const float4*>(&bias[col0 + tx * 4]);
    #pragma unroll
    for (int i = 0; i < 4; ++i) {
        const int gr = row0 + ty * 4 + i;
        float4 o;
        o.x = acc[i][0] + bias4.x;
        o.y = acc[i][1] + bias4.y;
        o.z = acc[i][2] + bias4.z;
        o.w = acc[i][3] + bias4.w;
        *reinterpret_cast<float4*>(&out[(size_t)gr * D_ + col0 + tx * 4]) = o;
    }
}

// ---------------------------------------------------------------------------
// MFMA flash attention. Grid (N/64, B*H), 256 thr = 4 waves.
// Wave w owns q-rows [w*16, w*16+16). Per 64-key tile:
//   S(16x64) = Q K^T  : 2 mfma_16x16x32_bf16 per 16-col tile (K row-major LDS)
//   online softmax on C-layout regs (row=quad*4+reg, col=lane&15),
//   row reductions via shfl_xor{1,2,4,8} within the quad's 16 lanes
//   P -> wave-private LDS bf16, row-rotated by q*8 (bank spread, 16B chunks)
//   O(16x64) += P V   : B-frag from V staged TRANSPOSED ([d][k] rows, +8 pad)
// m/l state per accumulator reg (4 q-rows/lane), replicated across the quad.
// ---------------------------------------------------------------------------
__global__ __launch_bounds__(256) void attn(
        const __bf16* __restrict__ Q, const __bf16* __restrict__ K,
        const __bf16* __restrict__ Vt, float* __restrict__ ctx)
{
    const int qb = (N_ / 64 - 1) - blockIdx.x;   // heavy tiles dispatched first
    const int bh = blockIdx.y;
    const int tid = threadIdx.x;
    const int w = tid >> 6;
    const int lane = tid & 63;
    const int l15 = lane & 15;
    const int quad = lane >> 4;

    __shared__ __align__(16) __bf16 Ks[64 * 72];      // [key][d], +8 pad
    __shared__ __align__(16) __bf16 Vs[64 * 72];      // [d][key], +8 pad
    __shared__ __align__(16) __bf16 Ps[4][16 * 64];   // wave-private P

    // Q fragments, held for the whole block
    const size_t qrow = ((size_t)bh * N_ + qb * 64 + w * 16 + l15) * DH_;
    const bf16x8 aq0 = *reinterpret_cast<const bf16x8*>(Q + qrow + quad * 8);
    const bf16x8 aq1 = *reinterpret_cast<const bf16x8*>(Q + qrow + 32 + quad * 8);

    f32x4 acc_o[4] = {};
    float m_run[4] = {-INFINITY, -INFINITY, -INFINITY, -INFINITY};
    float l_run[4] = {0.f, 0.f, 0.f, 0.f};
    const float scale = 0.125f;   // 1/sqrt(64)

    for (int kb = 0; kb <= qb; ++kb) {
        __syncthreads();   // previous tile's MFMA reads done
        {
            const __bf16* Kg = K + ((size_t)bh * N_ + kb * 64) * DH_;
            const __bf16* Vg = Vt + (size_t)bh * DH_ * N_ + kb * 64;
            #pragma unroll
            for (int it = 0; it < 2; ++it) {
                const int idx = it * 256 + tid;      // 512 chunks of 8 bf16
                const int rr = idx >> 3, c8 = idx & 7;
                *reinterpret_cast<float4*>(&Ks[rr * 72 + c8 * 8]) =
                    *reinterpret_cast<const float4*>(Kg + rr * DH_ + c8 * 8);
                *reinterpret_cast<float4*>(&Vs[rr * 72 + c8 * 8]) =
                    *reinterpret_cast<const float4*>(Vg + (size_t)rr * N_ + c8 * 8);
            }
        }
        __syncthreads();

        // --- S = Q K^T ---
        float sv[4][4];
        #pragma unroll
        for (int ct = 0; ct < 4; ++ct) {
            const bf16x8 b0 = *reinterpret_cast<const bf16x8*>(
                &Ks[(ct * 16 + l15) * 72 + quad * 8]);
            const bf16x8 b1 = *reinterpret_cast<const bf16x8*>(
                &Ks[(ct * 16 + l15) * 72 + 32 + quad * 8]);
            f32x4 t = {};
            t = __builtin_amdgcn_mfma_f32_16x16x32_bf16(aq0, b0, t, 0, 0, 0);
            t = __builtin_amdgcn_mfma_f32_16x16x32_bf16(aq1, b1, t, 0, 0, 0);
            #pragma unroll
            for (int i = 0; i < 4; ++i) sv[ct][i] = t[i] * scale;
        }

        if (kb == qb) {   // causal mask within the diagonal tile
            #pragma unroll
            for (int ct = 0; ct < 4; ++ct) {
                const int kg = ct * 16 + l15;
                #pragma unroll
                for (int i = 0; i < 4; ++i) {
                    const int qg = w * 16 + quad * 4 + i;
                    if (kg > qg) sv[ct][i] = -INFINITY;
                }
            }
        }

        // --- online softmax ---
        float alpha[4];
        #pragma unroll
        for (int i = 0; i < 4; ++i) {
            float m = fmaxf(fmaxf(sv[0][i], sv[1][i]), fmaxf(sv[2][i], sv[3][i]));
            m = fmaxf(m, __shfl_xor(m, 1));
            m = fmaxf(m, __shfl_xor(m, 2));
            m = fmaxf(m, __shfl_xor(m, 4));
            m = fmaxf(m, __shfl_xor(m, 8));
            const float m_new = fmaxf(m_run[i], m);
            alpha[i] = __expf(m_run[i] - m_new);   // 0 on first tile
            m_run[i] = m_new;
        }
        float rs[4] = {0.f, 0.f, 0.f, 0.f};
        #pragma unroll
        for (int ct = 0; ct < 4; ++ct)
            #pragma unroll
            for (int i = 0; i < 4; ++i) {
                const float p = __expf(sv[ct][i] - m_run[i]);
                sv[ct][i] = p;
                rs[i] += p;
            }
        #pragma unroll
        for (int i = 0; i < 4; ++i) {
            float r = rs[i];
            r += __shfl_xor(r, 1);
            r += __shfl_xor(r, 2);
            r += __shfl_xor(r, 4);
            r += __shfl_xor(r, 8);
            l_run[i] = l_run[i] * alpha[i] + r;
        }

        // --- P to wave-private LDS (row-rotated by q*8) ---
        __bf16* Pw = Ps[w];
        #pragma unroll
        for (int ct = 0; ct < 4; ++ct)
            #pragma unroll
            for (int i = 0; i < 4; ++i) {
                const int q = quad * 4 + i;
                const int col = (ct * 16 + l15 + q * 8) & 63;
                Pw[q * 64 + col] = (__bf16)sv[ct][i];
            }

        // --- O = O*alpha + P V ---
        #pragma unroll
        for (int ct = 0; ct < 4; ++ct) {
            f32x4 t = acc_o[ct];
            #pragma unroll
            for (int i = 0; i < 4; ++i) t[i] *= alpha[i];
            acc_o[ct] = t;
        }
        const bf16x8 ap0 = *reinterpret_cast<const bf16x8*>(
            &Pw[l15 * 64 + ((quad * 8 + l15 * 8) & 63)]);
        const bf16x8 ap1 = *reinterpret_cast<const bf16x8*>(
            &Pw[l15 * 64 + ((32 + quad * 8 + l15 * 8) & 63)]);
        #pragma unroll
        for (int ct = 0; ct < 4; ++ct) {
            const bf16x8 b0 = *reinterpret_cast<const bf16x8*>(
                &Vs[(ct * 16 + l15) * 72 + quad * 8]);
            const bf16x8 b1 = *reinterpret_cast<const bf16x8*>(
                &Vs[(ct * 16 + l15) * 72 + 32 + quad * 8]);
            f32x4 t = acc_o[ct];
            t = __builtin_amdgcn_mfma_f32_16x16x32_bf16(ap0, b0, t, 0, 0, 0);
            t = __builtin_amdgcn_mfma_f32_16x16x32_bf16(ap1, b1, t, 0, 0, 0);
            acc_o[ct] = t;
        }
    }

    // --- normalize, write ctx (B,N,D) fp32 ---
    const int b = bh >> 4, h = bh & 15;
    const int n0 = qb * 64 + w * 16 + quad * 4;
    #pragma unroll
    for (int i = 0; i < 4; ++i) {
        const float inv = 1.0f / l_run[i];
        float* dst = ctx + ((size_t)b * N_ + n0 + i) * D_ + h * DH_;
        #pragma unroll
        for (int ct = 0; ct < 4; ++ct)
            dst[ct * 16 + l15] = acc_o[ct][i] * inv;
    }
}

extern "C" void kernel_launch(void* const* d_in, const int* in_sizes, int n_in,
                              void* d_out, int out_size, void* d_ws, size_t ws_size,
                              hipStream_t stream) {
    const float* x  = (const float*)d_in[0];
    const float* Wq = (const float*)d_in[1];
    const float* bq = (const float*)d_in[2];
    const float* Wk = (const float*)d_in[3];
    const float* bk = (const float*)d_in[4];
    const float* Wv = (const float*)d_in[5];
    const float* bv = (const float*)d_in[6];
    const float* Wo = (const float*)d_in[7];
    const float* bo = (const float*)d_in[8];
    float* out = (float*)d_out;

    // ws: Q,K bf16 (B,H,N,DH) | V bf16 (B,H,DH,N) | ctx fp32 (B,N,D) = 84 MB
    __bf16* q  = (__bf16*)d_ws;
    __bf16* k  = q + (size_t)M_ * D_;
    __bf16* vt = k + (size_t)M_ * D_;
    float* ctx = (float*)(vt + (size_t)M_ * D_);

    qkv_gemm<<<dim3(M_ / 64, D_ / 64, 3), 256, 0, stream>>>(
        x, Wq, bq, Wk, bk, Wv, bv, q, k, vt);
    attn<<<dim3(N_ / 64, B_ * H_), 256, 0, stream>>>(q, k, vt, ctx);
    out_gemm<<<dim3(M_ / 64, D_ / 64), 256, 0, stream>>>(ctx, Wo, bo, out);
}

// Round 3
// 441.677 us; speedup vs baseline: 8.0224x; 2.8220x over previous
//
#include <hip/hip_runtime.h>
#include <hip/hip_bf16.h>
#include <math.h>

namespace {
constexpr int B_ = 4, N_ = 2048, D_ = 1024, H_ = 16, DH_ = 64;
constexpr int M_ = B_ * N_;   // 8192 rows of x
}

typedef __bf16 bf16x8 __attribute__((ext_vector_type(8)));
typedef __bf16 bf16x4 __attribute__((ext_vector_type(4)));
typedef float  f32x4  __attribute__((ext_vector_type(4)));

__device__ inline void async_copy16(const void* g, void* l) {
    __builtin_amdgcn_global_load_lds(
        (const __attribute__((address_space(1))) unsigned int*)g,
        (__attribute__((address_space(3))) unsigned int*)l, 16, 0, 0);
}

// XOR swizzle: logical 16B-chunk column (0..3) <-> physical, keyed by row.
__device__ inline int swz(int row, int c) {
    return c ^ (row & 3) ^ ((row >> 2) & 3);
}

// ---------------------------------------------------------------------------
// cast x (fp32 -> bf16), 8 elements/thread
// ---------------------------------------------------------------------------
__global__ __launch_bounds__(256) void cast_x(
        const float* __restrict__ x, __bf16* __restrict__ xb)
{
    const size_t i = ((size_t)blockIdx.x * 256 + threadIdx.x) * 8;
    const float4 a = *reinterpret_cast<const float4*>(x + i);
    const float4 b = *reinterpret_cast<const float4*>(x + i + 4);
    bf16x8 o;
    o[0] = (__bf16)a.x; o[1] = (__bf16)a.y; o[2] = (__bf16)a.z; o[3] = (__bf16)a.w;
    o[4] = (__bf16)b.x; o[5] = (__bf16)b.y; o[6] = (__bf16)b.z; o[7] = (__bf16)b.w;
    *reinterpret_cast<bf16x8*>(xb + i) = o;
}

// ---------------------------------------------------------------------------
// cast+transpose weights: W[k][n] fp32 -> Wt[n][k] bf16.
// Wq/Wk/Wv pack into wqkvt rows [z*1024, z*1024+1024); Wo -> wot.
// grid (16,16,4), 64x64 tiles via LDS.
// ---------------------------------------------------------------------------
__global__ __launch_bounds__(256) void cast_w(
        const float* __restrict__ Wq, const float* __restrict__ Wk,
        const float* __restrict__ Wv, const float* __restrict__ Wo,
        __bf16* __restrict__ wqkvt, __bf16* __restrict__ wot)
{
    __shared__ float t[64][65];
    const int z = blockIdx.z;
    const float* W = (z == 0) ? Wq : (z == 1) ? Wk : (z == 2) ? Wv : Wo;
    __bf16* dst = (z < 3) ? (wqkvt + (size_t)z * D_ * D_) : wot;
    const int k0 = blockIdx.x * 64, n0 = blockIdx.y * 64;
    const int tid = threadIdx.x;
    #pragma unroll
    for (int p = 0; p < 16; ++p) {
        const int idx = p * 256 + tid;
        const int r = idx >> 6, c = idx & 63;
        t[r][c] = W[(size_t)(k0 + r) * D_ + n0 + c];
    }
    __syncthreads();
    #pragma unroll
    for (int p = 0; p < 16; ++p) {
        const int idx = p * 256 + tid;
        const int r = idx >> 6, c = idx & 63;
        dst[(size_t)(n0 + r) * D_ + k0 + c] = (__bf16)t[c][r];
    }
}

// ---------------------------------------------------------------------------
// bf16 MFMA GEMM, 128x128 tile, BK=32, 256 thr = 4 waves (each a 64x64
// quadrant = 4x4 frags of mfma_f32_16x16x32_bf16). A: [M][K] bf16 row-major,
// B: W^T [N][K] bf16. global_load_lds(16B) staging, XOR-swizzled chunk layout
// (no padding allowed with lds-direct loads; swizzle gives 2-way = free).
// QKV variant: N=3072 packed; epilogue -> q/k (B,H,N,DH), v^T (B,H,DH,N) bf16.
// ---------------------------------------------------------------------------
__global__ __launch_bounds__(256) void qkv_mfma(
        const __bf16* __restrict__ A, const __bf16* __restrict__ Bt,
        const float* __restrict__ bq, const float* __restrict__ bk,
        const float* __restrict__ bv,
        __bf16* __restrict__ qo, __bf16* __restrict__ ko, __bf16* __restrict__ vo)
{
    __shared__ __align__(16) __bf16 As[128 * 32];
    __shared__ __align__(16) __bf16 Bs[128 * 32];
    const int tid = threadIdx.x;
    const int w = tid >> 6, lane = tid & 63;
    const int l15 = lane & 15, quad = lane >> 4;
    const int tm = blockIdx.x * 128;
    const int tn = blockIdx.y * 128;

    f32x4 acc[4][4] = {};

    for (int k0 = 0; k0 < D_; k0 += 32) {
        __syncthreads();
        #pragma unroll
        for (int it = 0; it < 2; ++it) {
            const int c = it * 256 + tid;
            const int r = c >> 2, pc = c & 3;
            const int lc = swz(r, pc);
            async_copy16(A + (size_t)(tm + r) * D_ + k0 + lc * 8, As + c * 8);
            async_copy16(Bt + (size_t)(tn + r) * D_ + k0 + lc * 8, Bs + c * 8);
        }
        __syncthreads();

        bf16x8 af[4], bfr[4];
        #pragma unroll
        for (int t = 0; t < 4; ++t) {
            const int row = (w >> 1) * 64 + t * 16 + l15;
            af[t] = *reinterpret_cast<const bf16x8*>(
                As + (row * 4 + swz(row, quad)) * 8);
            const int col = (w & 1) * 64 + t * 16 + l15;
            bfr[t] = *reinterpret_cast<const bf16x8*>(
                Bs + (col * 4 + swz(col, quad)) * 8);
        }
        #pragma unroll
        for (int mt = 0; mt < 4; ++mt)
            #pragma unroll
            for (int nt = 0; nt < 4; ++nt)
                acc[mt][nt] = __builtin_amdgcn_mfma_f32_16x16x32_bf16(
                    af[mt], bfr[nt], acc[mt][nt], 0, 0, 0);
    }

    // --- epilogue ---
    const int z = blockIdx.y >> 3;                       // which matrix
    const float* bias = (z == 0) ? bq : (z == 1) ? bk : bv;
    const int col0 = (blockIdx.y & 7) * 128 + (w & 1) * 64;  // within matrix
    const int h = col0 >> 6;
    float bcol[4];
    #pragma unroll
    for (int nt = 0; nt < 4; ++nt) bcol[nt] = bias[col0 + nt * 16 + l15];
    const int gr0 = tm + (w >> 1) * 64;

    if (z < 2) {
        __bf16* dst = (z == 0) ? qo : ko;
        #pragma unroll
        for (int mt = 0; mt < 4; ++mt)
            #pragma unroll
            for (int i = 0; i < 4; ++i) {
                const int gr = gr0 + mt * 16 + quad * 4 + i;
                const int b = gr >> 11, tok = gr & (N_ - 1);
                __bf16* row = dst + ((size_t)(b * H_ + h) * N_ + tok) * DH_;
                #pragma unroll
                for (int nt = 0; nt < 4; ++nt)
                    row[nt * 16 + l15] = (__bf16)(acc[mt][nt][i] + bcol[nt]);
            }
    } else {
        #pragma unroll
        for (int mt = 0; mt < 4; ++mt) {
            const int gr = gr0 + mt * 16 + quad * 4;
            const int b = gr >> 11, tok = gr & (N_ - 1);
            #pragma unroll
            for (int nt = 0; nt < 4; ++nt) {
                const int dh = nt * 16 + l15;
                bf16x4 pv;
                #pragma unroll
                for (int i = 0; i < 4; ++i)
                    pv[i] = (__bf16)(acc[mt][nt][i] + bcol[nt]);
                *reinterpret_cast<bf16x4*>(
                    vo + ((size_t)(b * H_ + h) * DH_ + dh) * N_ + tok) = pv;
            }
        }
    }
}

// ---------------------------------------------------------------------------
// out = ctx(bf16, MxD) @ Wo + bo, fp32 output. Same GEMM core.
// ---------------------------------------------------------------------------
__global__ __launch_bounds__(256) void out_mfma(
        const __bf16* __restrict__ A, const __bf16* __restrict__ Bt,
        const float* __restrict__ bias, float* __restrict__ out)
{
    __shared__ __align__(16) __bf16 As[128 * 32];
    __shared__ __align__(16) __bf16 Bs[128 * 32];
    const int tid = threadIdx.x;
    const int w = tid >> 6, lane = tid & 63;
    const int l15 = lane & 15, quad = lane >> 4;
    const int tm = blockIdx.x * 128;
    const int tn = blockIdx.y * 128;

    f32x4 acc[4][4] = {};

    for (int k0 = 0; k0 < D_; k0 += 32) {
        __syncthreads();
        #pragma unroll
        for (int it = 0; it < 2; ++it) {
            const int c = it * 256 + tid;
            const int r = c >> 2, pc = c & 3;
            const int lc = swz(r, pc);
            async_copy16(A + (size_t)(tm + r) * D_ + k0 + lc * 8, As + c * 8);
            async_copy16(Bt + (size_t)(tn + r) * D_ + k0 + lc * 8, Bs + c * 8);
        }
        __syncthreads();

        bf16x8 af[4], bfr[4];
        #pragma unroll
        for (int t = 0; t < 4; ++t) {
            const int row = (w >> 1) * 64 + t * 16 + l15;
            af[t] = *reinterpret_cast<const bf16x8*>(
                As + (row * 4 + swz(row, quad)) * 8);
            const int col = (w & 1) * 64 + t * 16 + l15;
            bfr[t] = *reinterpret_cast<const bf16x8*>(
                Bs + (col * 4 + swz(col, quad)) * 8);
        }
        #pragma unroll
        for (int mt = 0; mt < 4; ++mt)
            #pragma unroll
            for (int nt = 0; nt < 4; ++nt)
                acc[mt][nt] = __builtin_amdgcn_mfma_f32_16x16x32_bf16(
                    af[mt], bfr[nt], acc[mt][nt], 0, 0, 0);
    }

    const int col0 = tn + (w & 1) * 64;
    float bcol[4];
    #pragma unroll
    for (int nt = 0; nt < 4; ++nt) bcol[nt] = bias[col0 + nt * 16 + l15];
    const int gr0 = tm + (w >> 1) * 64;
    #pragma unroll
    for (int mt = 0; mt < 4; ++mt)
        #pragma unroll
        for (int i = 0; i < 4; ++i) {
            const int gr = gr0 + mt * 16 + quad * 4 + i;
            float* row = out + (size_t)gr * D_;
            #pragma unroll
            for (int nt = 0; nt < 4; ++nt)
                row[col0 + nt * 16 + l15] = acc[mt][nt][i] + bcol[nt];
        }
}

// ---------------------------------------------------------------------------
// MFMA flash attention (unchanged from R1 except bf16 ctx output).
// ---------------------------------------------------------------------------
__global__ __launch_bounds__(256) void attn(
        const __bf16* __restrict__ Q, const __bf16* __restrict__ K,
        const __bf16* __restrict__ Vt, __bf16* __restrict__ ctx)
{
    const int qb = (N_ / 64 - 1) - blockIdx.x;   // heavy tiles first
    const int bh = blockIdx.y;
    const int tid = threadIdx.x;
    const int w = tid >> 6;
    const int lane = tid & 63;
    const int l15 = lane & 15;
    const int quad = lane >> 4;

    __shared__ __align__(16) __bf16 Ks[64 * 72];      // [key][d], +8 pad
    __shared__ __align__(16) __bf16 Vs[64 * 72];      // [d][key], +8 pad
    __shared__ __align__(16) __bf16 Ps[4][16 * 64];   // wave-private P

    const size_t qrow = ((size_t)bh * N_ + qb * 64 + w * 16 + l15) * DH_;
    const bf16x8 aq0 = *reinterpret_cast<const bf16x8*>(Q + qrow + quad * 8);
    const bf16x8 aq1 = *reinterpret_cast<const bf16x8*>(Q + qrow + 32 + quad * 8);

    f32x4 acc_o[4] = {};
    float m_run[4] = {-INFINITY, -INFINITY, -INFINITY, -INFINITY};
    float l_run[4] = {0.f, 0.f, 0.f, 0.f};
    const float scale = 0.125f;   // 1/sqrt(64)

    for (int kb = 0; kb <= qb; ++kb) {
        __syncthreads();
        {
            const __bf16* Kg = K + ((size_t)bh * N_ + kb * 64) * DH_;
            const __bf16* Vg = Vt + (size_t)bh * DH_ * N_ + kb * 64;
            #pragma unroll
            for (int it = 0; it < 2; ++it) {
                const int idx = it * 256 + tid;
                const int rr = idx >> 3, c8 = idx & 7;
                *reinterpret_cast<float4*>(&Ks[rr * 72 + c8 * 8]) =
                    *reinterpret_cast<const float4*>(Kg + rr * DH_ + c8 * 8);
                *reinterpret_cast<float4*>(&Vs[rr * 72 + c8 * 8]) =
                    *reinterpret_cast<const float4*>(Vg + (size_t)rr * N_ + c8 * 8);
            }
        }
        __syncthreads();

        float sv[4][4];
        #pragma unroll
        for (int ct = 0; ct < 4; ++ct) {
            const bf16x8 b0 = *reinterpret_cast<const bf16x8*>(
                &Ks[(ct * 16 + l15) * 72 + quad * 8]);
            const bf16x8 b1 = *reinterpret_cast<const bf16x8*>(
                &Ks[(ct * 16 + l15) * 72 + 32 + quad * 8]);
            f32x4 t = {};
            t = __builtin_amdgcn_mfma_f32_16x16x32_bf16(aq0, b0, t, 0, 0, 0);
            t = __builtin_amdgcn_mfma_f32_16x16x32_bf16(aq1, b1, t, 0, 0, 0);
            #pragma unroll
            for (int i = 0; i < 4; ++i) sv[ct][i] = t[i] * scale;
        }

        if (kb == qb) {
            #pragma unroll
            for (int ct = 0; ct < 4; ++ct) {
                const int kg = ct * 16 + l15;
                #pragma unroll
                for (int i = 0; i < 4; ++i) {
                    const int qg = w * 16 + quad * 4 + i;
                    if (kg > qg) sv[ct][i] = -INFINITY;
                }
            }
        }

        float alpha[4];
        #pragma unroll
        for (int i = 0; i < 4; ++i) {
            float m = fmaxf(fmaxf(sv[0][i], sv[1][i]), fmaxf(sv[2][i], sv[3][i]));
            m = fmaxf(m, __shfl_xor(m, 1));
            m = fmaxf(m, __shfl_xor(m, 2));
            m = fmaxf(m, __shfl_xor(m, 4));
            m = fmaxf(m, __shfl_xor(m, 8));
            const float m_new = fmaxf(m_run[i], m);
            alpha[i] = __expf(m_run[i] - m_new);
            m_run[i] = m_new;
        }
        float rs[4] = {0.f, 0.f, 0.f, 0.f};
        #pragma unroll
        for (int ct = 0; ct < 4; ++ct)
            #pragma unroll
            for (int i = 0; i < 4; ++i) {
                const float p = __expf(sv[ct][i] - m_run[i]);
                sv[ct][i] = p;
                rs[i] += p;
            }
        #pragma unroll
        for (int i = 0; i < 4; ++i) {
            float r = rs[i];
            r += __shfl_xor(r, 1);
            r += __shfl_xor(r, 2);
            r += __shfl_xor(r, 4);
            r += __shfl_xor(r, 8);
            l_run[i] = l_run[i] * alpha[i] + r;
        }

        __bf16* Pw = Ps[w];
        #pragma unroll
        for (int ct = 0; ct < 4; ++ct)
            #pragma unroll
            for (int i = 0; i < 4; ++i) {
                const int q = quad * 4 + i;
                const int col = (ct * 16 + l15 + q * 8) & 63;
                Pw[q * 64 + col] = (__bf16)sv[ct][i];
            }

        #pragma unroll
        for (int ct = 0; ct < 4; ++ct) {
            f32x4 t = acc_o[ct];
            #pragma unroll
            for (int i = 0; i < 4; ++i) t[i] *= alpha[i];
            acc_o[ct] = t;
        }
        const bf16x8 ap0 = *reinterpret_cast<const bf16x8*>(
            &Pw[l15 * 64 + ((quad * 8 + l15 * 8) & 63)]);
        const bf16x8 ap1 = *reinterpret_cast<const bf16x8*>(
            &Pw[l15 * 64 + ((32 + quad * 8 + l15 * 8) & 63)]);
        #pragma unroll
        for (int ct = 0; ct < 4; ++ct) {
            const bf16x8 b0 = *reinterpret_cast<const bf16x8*>(
                &Vs[(ct * 16 + l15) * 72 + quad * 8]);
            const bf16x8 b1 = *reinterpret_cast<const bf16x8*>(
                &Vs[(ct * 16 + l15) * 72 + 32 + quad * 8]);
            f32x4 t = acc_o[ct];
            t = __builtin_amdgcn_mfma_f32_16x16x32_bf16(ap0, b0, t, 0, 0, 0);
            t = __builtin_amdgcn_mfma_f32_16x16x32_bf16(ap1, b1, t, 0, 0, 0);
            acc_o[ct] = t;
        }
    }

    const int b = bh >> 4, h = bh & 15;
    const int n0 = qb * 64 + w * 16 + quad * 4;
    #pragma unroll
    for (int i = 0; i < 4; ++i) {
        const float inv = 1.0f / l_run[i];
        __bf16* dst = ctx + ((size_t)b * N_ + n0 + i) * D_ + h * DH_;
        #pragma unroll
        for (int ct = 0; ct < 4; ++ct)
            dst[ct * 16 + l15] = (__bf16)(acc_o[ct][i] * inv);
    }
}

extern "C" void kernel_launch(void* const* d_in, const int* in_sizes, int n_in,
                              void* d_out, int out_size, void* d_ws, size_t ws_size,
                              hipStream_t stream) {
    const float* x  = (const float*)d_in[0];
    const float* Wq = (const float*)d_in[1];
    const float* bq = (const float*)d_in[2];
    const float* Wk = (const float*)d_in[3];
    const float* bk = (const float*)d_in[4];
    const float* Wv = (const float*)d_in[5];
    const float* bv = (const float*)d_in[6];
    const float* Wo = (const float*)d_in[7];
    const float* bo = (const float*)d_in[8];
    float* out = (float*)d_out;

    // ws (bf16 elements): xb | wqkvt | wot | q | k | vt | ctx  = ~92 MB
    __bf16* xb    = (__bf16*)d_ws;
    __bf16* wqkvt = xb + (size_t)M_ * D_;
    __bf16* wot   = wqkvt + (size_t)3 * D_ * D_;
    __bf16* q     = wot + (size_t)D_ * D_;
    __bf16* k     = q + (size_t)M_ * D_;
    __bf16* vt    = k + (size_t)M_ * D_;
    __bf16* ctx   = vt + (size_t)M_ * D_;

    cast_x<<<dim3(M_ * D_ / (256 * 8)), 256, 0, stream>>>(x, xb);
    cast_w<<<dim3(16, 16, 4), 256, 0, stream>>>(Wq, Wk, Wv, Wo, wqkvt, wot);
    qkv_mfma<<<dim3(M_ / 128, 3 * D_ / 128), 256, 0, stream>>>(
        xb, wqkvt, bq, bk, bv, q, k, vt);
    attn<<<dim3(N_ / 64, B_ * H_), 256, 0, stream>>>(q, k, vt, ctx);
    out_mfma<<<dim3(M_ / 128, D_ / 128), 256, 0, stream>>>(ctx, wot, bo, out);
}

// Round 4
// 308.525 us; speedup vs baseline: 11.4846x; 1.4316x over previous
//
#include <hip/hip_runtime.h>
#include <hip/hip_bf16.h>
#include <math.h>

namespace {
constexpr int B_ = 4, N_ = 2048, D_ = 1024, H_ = 16, DH_ = 64;
constexpr int M_ = B_ * N_;   // 8192 rows of x
}

typedef __bf16 bf16x8 __attribute__((ext_vector_type(8)));
typedef __bf16 bf16x4 __attribute__((ext_vector_type(4)));
typedef float  f32x4  __attribute__((ext_vector_type(4)));

__device__ inline void async_copy16(const void* g, void* l) {
    __builtin_amdgcn_global_load_lds(
        (const __attribute__((address_space(1))) unsigned int*)g,
        (__attribute__((address_space(3))) unsigned int*)l, 16, 0, 0);
}

// XOR swizzle: logical 16B-chunk column (0..3) <-> physical, keyed by row.
__device__ inline int swz(int row, int c) {
    return c ^ (row & 3) ^ ((row >> 2) & 3);
}

// ---------------------------------------------------------------------------
// cast x (fp32 -> bf16), 8 elements/thread
// ---------------------------------------------------------------------------
__global__ __launch_bounds__(256) void cast_x(
        const float* __restrict__ x, __bf16* __restrict__ xb)
{
    const size_t i = ((size_t)blockIdx.x * 256 + threadIdx.x) * 8;
    const float4 a = *reinterpret_cast<const float4*>(x + i);
    const float4 b = *reinterpret_cast<const float4*>(x + i + 4);
    bf16x8 o;
    o[0] = (__bf16)a.x; o[1] = (__bf16)a.y; o[2] = (__bf16)a.z; o[3] = (__bf16)a.w;
    o[4] = (__bf16)b.x; o[5] = (__bf16)b.y; o[6] = (__bf16)b.z; o[7] = (__bf16)b.w;
    *reinterpret_cast<bf16x8*>(xb + i) = o;
}

// ---------------------------------------------------------------------------
// cast+transpose weights: W[k][n] fp32 -> Wt[n][k] bf16.
// ---------------------------------------------------------------------------
__global__ __launch_bounds__(256) void cast_w(
        const float* __restrict__ Wq, const float* __restrict__ Wk,
        const float* __restrict__ Wv, const float* __restrict__ Wo,
        __bf16* __restrict__ wqkvt, __bf16* __restrict__ wot)
{
    __shared__ float t[64][65];
    const int z = blockIdx.z;
    const float* W = (z == 0) ? Wq : (z == 1) ? Wk : (z == 2) ? Wv : Wo;
    __bf16* dst = (z < 3) ? (wqkvt + (size_t)z * D_ * D_) : wot;
    const int k0 = blockIdx.x * 64, n0 = blockIdx.y * 64;
    const int tid = threadIdx.x;
    #pragma unroll
    for (int p = 0; p < 16; ++p) {
        const int idx = p * 256 + tid;
        const int r = idx >> 6, c = idx & 63;
        t[r][c] = W[(size_t)(k0 + r) * D_ + n0 + c];
    }
    __syncthreads();
    #pragma unroll
    for (int p = 0; p < 16; ++p) {
        const int idx = p * 256 + tid;
        const int r = idx >> 6, c = idx & 63;
        dst[(size_t)(n0 + r) * D_ + k0 + c] = (__bf16)t[c][r];
    }
}

// ---------------------------------------------------------------------------
// bf16 MFMA GEMM, 128x128 tile, BK=32. QKV variant (N=3072 packed).
// Q epilogue folds the 1/sqrt(DH)=0.125 attention scale (exact in bf16).
// ---------------------------------------------------------------------------
__global__ __launch_bounds__(256) void qkv_mfma(
        const __bf16* __restrict__ A, const __bf16* __restrict__ Bt,
        const float* __restrict__ bq, const float* __restrict__ bk,
        const float* __restrict__ bv,
        __bf16* __restrict__ qo, __bf16* __restrict__ ko, __bf16* __restrict__ vo)
{
    __shared__ __align__(16) __bf16 As[128 * 32];
    __shared__ __align__(16) __bf16 Bs[128 * 32];
    const int tid = threadIdx.x;
    const int w = tid >> 6, lane = tid & 63;
    const int l15 = lane & 15, quad = lane >> 4;
    const int tm = blockIdx.x * 128;
    const int tn = blockIdx.y * 128;

    f32x4 acc[4][4] = {};

    for (int k0 = 0; k0 < D_; k0 += 32) {
        __syncthreads();
        #pragma unroll
        for (int it = 0; it < 2; ++it) {
            const int c = it * 256 + tid;
            const int r = c >> 2, pc = c & 3;
            const int lc = swz(r, pc);
            async_copy16(A + (size_t)(tm + r) * D_ + k0 + lc * 8, As + c * 8);
            async_copy16(Bt + (size_t)(tn + r) * D_ + k0 + lc * 8, Bs + c * 8);
        }
        __syncthreads();

        bf16x8 af[4], bfr[4];
        #pragma unroll
        for (int t = 0; t < 4; ++t) {
            const int row = (w >> 1) * 64 + t * 16 + l15;
            af[t] = *reinterpret_cast<const bf16x8*>(
                As + (row * 4 + swz(row, quad)) * 8);
            const int col = (w & 1) * 64 + t * 16 + l15;
            bfr[t] = *reinterpret_cast<const bf16x8*>(
                Bs + (col * 4 + swz(col, quad)) * 8);
        }
        #pragma unroll
        for (int mt = 0; mt < 4; ++mt)
            #pragma unroll
            for (int nt = 0; nt < 4; ++nt)
                acc[mt][nt] = __builtin_amdgcn_mfma_f32_16x16x32_bf16(
                    af[mt], bfr[nt], acc[mt][nt], 0, 0, 0);
    }

    const int z = blockIdx.y >> 3;
    const float* bias = (z == 0) ? bq : (z == 1) ? bk : bv;
    const int col0 = (blockIdx.y & 7) * 128 + (w & 1) * 64;
    const int h = col0 >> 6;
    float bcol[4];
    #pragma unroll
    for (int nt = 0; nt < 4; ++nt) bcol[nt] = bias[col0 + nt * 16 + l15];
    const int gr0 = tm + (w >> 1) * 64;

    if (z < 2) {
        __bf16* dst = (z == 0) ? qo : ko;
        const float sc = (z == 0) ? 0.125f : 1.0f;   // fold attn scale into Q
        #pragma unroll
        for (int mt = 0; mt < 4; ++mt)
            #pragma unroll
            for (int i = 0; i < 4; ++i) {
                const int gr = gr0 + mt * 16 + quad * 4 + i;
                const int b = gr >> 11, tok = gr & (N_ - 1);
                __bf16* row = dst + ((size_t)(b * H_ + h) * N_ + tok) * DH_;
                #pragma unroll
                for (int nt = 0; nt < 4; ++nt)
                    row[nt * 16 + l15] = (__bf16)((acc[mt][nt][i] + bcol[nt]) * sc);
            }
    } else {
        #pragma unroll
        for (int mt = 0; mt < 4; ++mt) {
            const int gr = gr0 + mt * 16 + quad * 4;
            const int b = gr >> 11, tok = gr & (N_ - 1);
            #pragma unroll
            for (int nt = 0; nt < 4; ++nt) {
                const int dh = nt * 16 + l15;
                bf16x4 pv;
                #pragma unroll
                for (int i = 0; i < 4; ++i)
                    pv[i] = (__bf16)(acc[mt][nt][i] + bcol[nt]);
                *reinterpret_cast<bf16x4*>(
                    vo + ((size_t)(b * H_ + h) * DH_ + dh) * N_ + tok) = pv;
            }
        }
    }
}

// ---------------------------------------------------------------------------
// out = ctx(bf16, MxD) @ Wo + bo, fp32 output.
// ---------------------------------------------------------------------------
__global__ __launch_bounds__(256) void out_mfma(
        const __bf16* __restrict__ A, const __bf16* __restrict__ Bt,
        const float* __restrict__ bias, float* __restrict__ out)
{
    __shared__ __align__(16) __bf16 As[128 * 32];
    __shared__ __align__(16) __bf16 Bs[128 * 32];
    const int tid = threadIdx.x;
    const int w = tid >> 6, lane = tid & 63;
    const int l15 = lane & 15, quad = lane >> 4;
    const int tm = blockIdx.x * 128;
    const int tn = blockIdx.y * 128;

    f32x4 acc[4][4] = {};

    for (int k0 = 0; k0 < D_; k0 += 32) {
        __syncthreads();
        #pragma unroll
        for (int it = 0; it < 2; ++it) {
            const int c = it * 256 + tid;
            const int r = c >> 2, pc = c & 3;
            const int lc = swz(r, pc);
            async_copy16(A + (size_t)(tm + r) * D_ + k0 + lc * 8, As + c * 8);
            async_copy16(Bt + (size_t)(tn + r) * D_ + k0 + lc * 8, Bs + c * 8);
        }
        __syncthreads();

        bf16x8 af[4], bfr[4];
        #pragma unroll
        for (int t = 0; t < 4; ++t) {
            const int row = (w >> 1) * 64 + t * 16 + l15;
            af[t] = *reinterpret_cast<const bf16x8*>(
                As + (row * 4 + swz(row, quad)) * 8);
            const int col = (w & 1) * 64 + t * 16 + l15;
            bfr[t] = *reinterpret_cast<const bf16x8*>(
                Bs + (col * 4 + swz(col, quad)) * 8);
        }
        #pragma unroll
        for (int mt = 0; mt < 4; ++mt)
            #pragma unroll
            for (int nt = 0; nt < 4; ++nt)
                acc[mt][nt] = __builtin_amdgcn_mfma_f32_16x16x32_bf16(
                    af[mt], bfr[nt], acc[mt][nt], 0, 0, 0);
    }

    const int col0 = tn + (w & 1) * 64;
    float bcol[4];
    #pragma unroll
    for (int nt = 0; nt < 4; ++nt) bcol[nt] = bias[col0 + nt * 16 + l15];
    const int gr0 = tm + (w >> 1) * 64;
    #pragma unroll
    for (int mt = 0; mt < 4; ++mt)
        #pragma unroll
        for (int i = 0; i < 4; ++i) {
            const int gr = gr0 + mt * 16 + quad * 4 + i;
            float* row = out + (size_t)gr * D_;
            #pragma unroll
            for (int nt = 0; nt < 4; ++nt)
                row[col0 + nt * 16 + l15] = acc[mt][nt][i] + bcol[nt];
        }
}

// ---------------------------------------------------------------------------
// MFMA flash attention v2. Grid (N/128, B*H), 256 thr = 4 waves.
// Block = 128 q-rows; wave w owns rows [w*32, w*32+32) as 2 chunks of 16.
// Computes S^T = K Q^T (A-frag = K rows from LDS, B-frag = Q regs), so in the
// C-layout q = lane&15: softmax row-reduce = in-lane over 16 values + 2
// shuffles (xor 16/32). P packs to bf16x4 -> 4 ds_write_b64; PV uses P as
// A-frag (m=q=lane&15 matches) and V^T rows as B-frag. alpha/l transposed to
// the O-accumulator row layout (q=quad*4+i) via 4 __shfl.
// K/V staged with global_load_lds(16B), chunk-XOR-swizzled on the global side
// (LDS slots stay lane-contiguous as HW requires); frag reads min-phase.
// ---------------------------------------------------------------------------
__global__ __launch_bounds__(256, 4) void attn(
        const __bf16* __restrict__ Q, const __bf16* __restrict__ K,
        const __bf16* __restrict__ Vt, __bf16* __restrict__ ctx)
{
    const int qb = (N_ / 128 - 1) - blockIdx.x;   // heavy blocks first
    const int bh = blockIdx.y;
    const int tid = threadIdx.x;
    const int w = tid >> 6, lane = tid & 63;
    const int l15 = lane & 15, quad = lane >> 4;
    const int qt0 = qb * 128;

    __shared__ __align__(16) __bf16 Ks[64 * 64];      // [key][d], chunk-swizzled
    __shared__ __align__(16) __bf16 Vs[64 * 64];      // [d][key], chunk-swizzled
    __shared__ __align__(16) __bf16 Ps[4][16 * 72];   // wave-private P, +8 pad

    // Q fragments (B-operand: n=q=l15, k=d=quad*8+j), held all block
    bf16x8 bq[2][2];
    #pragma unroll
    for (int qc = 0; qc < 2; ++qc) {
        const size_t base = ((size_t)bh * N_ + qt0 + w * 32 + qc * 16 + l15) * DH_;
        bq[qc][0] = *reinterpret_cast<const bf16x8*>(Q + base + quad * 8);
        bq[qc][1] = *reinterpret_cast<const bf16x8*>(Q + base + 32 + quad * 8);
    }

    f32x4 acc[2][4] = {};
    float m_run[2] = {-INFINITY, -INFINITY};
    float l_run[2] = {0.f, 0.f};

    const __bf16* Kg = K + (size_t)bh * N_ * DH_;
    const __bf16* Vg = Vt + (size_t)bh * DH_ * N_;
    const int nkb = 2 * qb + 2;
    const int sr = lane >> 3;      // row-in-group for staging
    const int sc = lane & 7;       // chunk slot for staging

    for (int kb = 0; kb < nkb; ++kb) {
        __syncthreads();
        #pragma unroll
        for (int j = 0; j < 2; ++j) {
            const int r = j * 32 + w * 8 + sr;
            const int cl = sc ^ (r & 7);               // logical chunk fetched
            async_copy16(Kg + (size_t)(kb * 64 + r) * DH_ + cl * 8,
                         Ks + (j * 256 + tid) * 8);
            async_copy16(Vg + (size_t)r * N_ + kb * 64 + cl * 8,
                         Vs + (j * 256 + tid) * 8);
        }
        __syncthreads();

        const bool diag = (kb >= 2 * qb);
        __bf16* Pw = Ps[w];

        #pragma unroll
        for (int qc = 0; qc < 2; ++qc) {
            // --- S^T = K Q^T : per ct tile, k=ct*16+quad*4+i, q=l15 ---
            f32x4 st[4];
            #pragma unroll
            for (int ct = 0; ct < 4; ++ct) {
                const int row = ct * 16 + l15;
                const bf16x8 ka0 = *reinterpret_cast<const bf16x8*>(
                    Ks + (row * 8 + (quad ^ (row & 7))) * 8);
                const bf16x8 ka1 = *reinterpret_cast<const bf16x8*>(
                    Ks + (row * 8 + ((quad + 4) ^ (row & 7))) * 8);
                f32x4 t = {};
                t = __builtin_amdgcn_mfma_f32_16x16x32_bf16(ka0, bq[qc][0], t, 0, 0, 0);
                t = __builtin_amdgcn_mfma_f32_16x16x32_bf16(ka1, bq[qc][1], t, 0, 0, 0);
                st[ct] = t;
            }
            if (diag) {
                const int q_glob = qt0 + w * 32 + qc * 16 + l15;
                #pragma unroll
                for (int ct = 0; ct < 4; ++ct)
                    #pragma unroll
                    for (int i = 0; i < 4; ++i) {
                        const int k_glob = kb * 64 + ct * 16 + quad * 4 + i;
                        if (k_glob > q_glob) st[ct][i] = -INFINITY;
                    }
            }

            // --- online softmax for q = l15 (16 values in-lane) ---
            float mt = st[0][0];
            #pragma unroll
            for (int ct = 0; ct < 4; ++ct)
                #pragma unroll
                for (int i = 0; i < 4; ++i) mt = fmaxf(mt, st[ct][i]);
            mt = fmaxf(mt, __shfl_xor(mt, 16));
            mt = fmaxf(mt, __shfl_xor(mt, 32));
            const float m_new = fmaxf(m_run[qc], mt);
            const float alpha = __expf(m_run[qc] - m_new);
            m_run[qc] = m_new;

            float rs = 0.f;
            bf16x4 pk[4];
            #pragma unroll
            for (int ct = 0; ct < 4; ++ct)
                #pragma unroll
                for (int i = 0; i < 4; ++i) {
                    const float p = __expf(st[ct][i] - m_new);
                    rs += p;
                    pk[ct][i] = (__bf16)p;
                }
            rs += __shfl_xor(rs, 16);
            rs += __shfl_xor(rs, 32);
            l_run[qc] = l_run[qc] * alpha + rs;

            // --- P -> LDS (4 b64 writes, conflict-free) ---
            #pragma unroll
            for (int ct = 0; ct < 4; ++ct)
                *reinterpret_cast<bf16x4*>(Pw + l15 * 72 + ct * 16 + quad * 4) =
                    pk[ct];

            // --- alpha to O row layout (q = quad*4+i) ---
            float aT[4];
            #pragma unroll
            for (int i = 0; i < 4; ++i) aT[i] = __shfl(alpha, quad * 4 + i);

            // --- O = O*alpha + P V ---
            const bf16x8 pa0 = *reinterpret_cast<const bf16x8*>(
                Pw + l15 * 72 + quad * 8);
            const bf16x8 pa1 = *reinterpret_cast<const bf16x8*>(
                Pw + l15 * 72 + 32 + quad * 8);
            #pragma unroll
            for (int ct = 0; ct < 4; ++ct) {
                const int row = ct * 16 + l15;
                const bf16x8 vb0 = *reinterpret_cast<const bf16x8*>(
                    Vs + (row * 8 + (quad ^ (row & 7))) * 8);
                const bf16x8 vb1 = *reinterpret_cast<const bf16x8*>(
                    Vs + (row * 8 + ((quad + 4) ^ (row & 7))) * 8);
                f32x4 t = acc[qc][ct];
                #pragma unroll
                for (int i = 0; i < 4; ++i) t[i] *= aT[i];
                t = __builtin_amdgcn_mfma_f32_16x16x32_bf16(pa0, vb0, t, 0, 0, 0);
                t = __builtin_amdgcn_mfma_f32_16x16x32_bf16(pa1, vb1, t, 0, 0, 0);
                acc[qc][ct] = t;
            }
        }
    }

    // --- normalize, write ctx (B,N,D) bf16 ---
    const int b = bh >> 4, h = bh & 15;
    #pragma unroll
    for (int qc = 0; qc < 2; ++qc) {
        const float linv = 1.0f / l_run[qc];
        float lT[4];
        #pragma unroll
        for (int i = 0; i < 4; ++i) lT[i] = __shfl(linv, quad * 4 + i);
        #pragma unroll
        for (int i = 0; i < 4; ++i) {
            const int row = qt0 + w * 32 + qc * 16 + quad * 4 + i;
            __bf16* dst = ctx + ((size_t)b * N_ + row) * D_ + h * DH_;
            #pragma unroll
            for (int ct = 0; ct < 4; ++ct)
                dst[ct * 16 + l15] = (__bf16)(acc[qc][ct][i] * lT[i]);
        }
    }
}

extern "C" void kernel_launch(void* const* d_in, const int* in_sizes, int n_in,
                              void* d_out, int out_size, void* d_ws, size_t ws_size,
                              hipStream_t stream) {
    const float* x  = (const float*)d_in[0];
    const float* Wq = (const float*)d_in[1];
    const float* bq = (const float*)d_in[2];
    const float* Wk = (const float*)d_in[3];
    const float* bk = (const float*)d_in[4];
    const float* Wv = (const float*)d_in[5];
    const float* bv = (const float*)d_in[6];
    const float* Wo = (const float*)d_in[7];
    const float* bo = (const float*)d_in[8];
    float* out = (float*)d_out;

    __bf16* xb    = (__bf16*)d_ws;
    __bf16* wqkvt = xb + (size_t)M_ * D_;
    __bf16* wot   = wqkvt + (size_t)3 * D_ * D_;
    __bf16* q     = wot + (size_t)D_ * D_;
    __bf16* k     = q + (size_t)M_ * D_;
    __bf16* vt    = k + (size_t)M_ * D_;
    __bf16* ctx   = vt + (size_t)M_ * D_;

    cast_x<<<dim3(M_ * D_ / (256 * 8)), 256, 0, stream>>>(x, xb);
    cast_w<<<dim3(16, 16, 4), 256, 0, stream>>>(Wq, Wk, Wv, Wo, wqkvt, wot);
    qkv_mfma<<<dim3(M_ / 128, 3 * D_ / 128), 256, 0, stream>>>(
        xb, wqkvt, bq, bk, bv, q, k, vt);
    attn<<<dim3(N_ / 128, B_ * H_), 256, 0, stream>>>(q, k, vt, ctx);
    out_mfma<<<dim3(M_ / 128, D_ / 128), 256, 0, stream>>>(ctx, wot, bo, out);
}